// Round 1
// baseline (1420.582 us; speedup 1.0000x reference)
//
#include <hip/hip_runtime.h>

typedef __attribute__((ext_vector_type(4))) float f32x4;

#define BH_  32
#define S_   2048
#define DK_  64
#define TQ_  8
#define NT_  256
// 1/sqrt(64) = 0.125

__global__ __launch_bounds__(NT_, 2)
void sdpa_fused_kernel(const float* __restrict__ q, const float* __restrict__ k,
                       const float* __restrict__ v, float* __restrict__ ctx,
                       float* __restrict__ attn)
{
    // padded +4 floats so the 4 r-groups in PV hit different banks
    __shared__ float q_s[TQ_][DK_];
    __shared__ float p_s[TQ_][S_ + 4];
    __shared__ float redmax[4][TQ_];
    __shared__ float redsum[4][TQ_];
    __shared__ float cpart[TQ_][DK_];

    const int bh   = blockIdx.x >> 8;   // 256 q-tiles per head
    const int qt   = blockIdx.x & 255;
    const int row0 = qt * TQ_;
    const int tid  = threadIdx.x;
    const int wave = tid >> 6;

    const float* qb = q + ((size_t)bh * S_ + row0) * DK_;
    const float* kb = k + (size_t)bh * DK_ * S_;
    const float* vb = v + (size_t)bh * S_ * DK_;

    // ---- stage Q tile (8 rows x 64) ----
    for (int i = tid; i < TQ_ * DK_; i += NT_)
        (&q_s[0][0])[i] = qb[i];
    __syncthreads();

    // ---- QK^T: each thread owns 8 consecutive columns c0..c0+7 for all 8 rows ----
    float acc[TQ_][8];
#pragma unroll
    for (int r = 0; r < TQ_; ++r)
#pragma unroll
        for (int j = 0; j < 8; ++j)
            acc[r][j] = 0.f;

    const int c0 = tid * 8;
    for (int d = 0; d < DK_; ++d) {
        f32x4 k0 = *(const f32x4*)(kb + (size_t)d * S_ + c0);
        f32x4 k1 = *(const f32x4*)(kb + (size_t)d * S_ + c0 + 4);
#pragma unroll
        for (int r = 0; r < TQ_; ++r) {
            float qv = q_s[r][d];
#pragma unroll
            for (int j = 0; j < 4; ++j) {
                acc[r][j]     = fmaf(qv, k0[j], acc[r][j]);
                acc[r][4 + j] = fmaf(qv, k1[j], acc[r][4 + j]);
            }
        }
    }

    // ---- scale + row max (wave shuffle + cross-wave LDS) ----
    float m[TQ_];
#pragma unroll
    for (int r = 0; r < TQ_; ++r) {
        float lm = -1e30f;
#pragma unroll
        for (int j = 0; j < 8; ++j) {
            acc[r][j] *= 0.125f;
            lm = fmaxf(lm, acc[r][j]);
        }
        for (int off = 32; off; off >>= 1)
            lm = fmaxf(lm, __shfl_xor(lm, off));
        if ((tid & 63) == 0) redmax[wave][r] = lm;
    }
    __syncthreads();
#pragma unroll
    for (int r = 0; r < TQ_; ++r)
        m[r] = fmaxf(fmaxf(redmax[0][r], redmax[1][r]),
                     fmaxf(redmax[2][r], redmax[3][r]));

    // ---- exp + row sum ----
#pragma unroll
    for (int r = 0; r < TQ_; ++r) {
        float ls = 0.f;
#pragma unroll
        for (int j = 0; j < 8; ++j) {
            acc[r][j] = __expf(acc[r][j] - m[r]);
            ls += acc[r][j];
        }
        for (int off = 32; off; off >>= 1)
            ls += __shfl_xor(ls, off);
        if ((tid & 63) == 0) redsum[wave][r] = ls;
    }
    __syncthreads();

    // ---- normalize; write attn (global) and p (LDS) ----
    float* attb = attn + ((size_t)bh * S_ + row0) * S_;
#pragma unroll
    for (int r = 0; r < TQ_; ++r) {
        float inv = 1.0f / (redsum[0][r] + redsum[1][r] + redsum[2][r] + redsum[3][r]);
        f32x4 p0, p1;
#pragma unroll
        for (int j = 0; j < 4; ++j) {
            p0[j] = acc[r][j] * inv;
            p1[j] = acc[r][4 + j] * inv;
        }
        *(f32x4*)(&p_s[r][c0])     = p0;
        *(f32x4*)(&p_s[r][c0 + 4]) = p1;
        *(f32x4*)(attb + (size_t)r * S_ + c0)     = p0;
        *(f32x4*)(attb + (size_t)r * S_ + c0 + 4) = p1;
    }
    __syncthreads();

    // ---- PV: thread -> (row r, d-quad dq, t-half); coalesced float4 v loads ----
    const int dq   = (tid & 15) * 4;
    const int rg   = tid >> 4;      // 0..15
    const int r    = rg & 7;
    const int half = rg >> 3;       // 0 or 1
    const int tbeg = half * (S_ / 2);

    f32x4 cacc = {0.f, 0.f, 0.f, 0.f};
    for (int t = tbeg; t < tbeg + S_ / 2; t += 4) {
        f32x4 pv = *(const f32x4*)(&p_s[r][t]);
#pragma unroll
        for (int i = 0; i < 4; ++i) {
            f32x4 vv = *(const f32x4*)(vb + (size_t)(t + i) * DK_ + dq);
            cacc[0] = fmaf(pv[i], vv[0], cacc[0]);
            cacc[1] = fmaf(pv[i], vv[1], cacc[1]);
            cacc[2] = fmaf(pv[i], vv[2], cacc[2]);
            cacc[3] = fmaf(pv[i], vv[3], cacc[3]);
        }
    }

    // combine the two t-halves through LDS
    if (half == 0)
        *(f32x4*)(&cpart[r][dq]) = cacc;
    __syncthreads();
    if (half == 1) {
        f32x4 other = *(const f32x4*)(&cpart[r][dq]);
        cacc[0] += other[0]; cacc[1] += other[1];
        cacc[2] += other[2]; cacc[3] += other[3];
        *(f32x4*)(ctx + ((size_t)bh * S_ + row0 + r) * DK_ + dq) = cacc;
    }
}

extern "C" void kernel_launch(void* const* d_in, const int* in_sizes, int n_in,
                              void* d_out, int out_size, void* d_ws, size_t ws_size,
                              hipStream_t stream)
{
    const float* q = (const float*)d_in[0];
    const float* k = (const float*)d_in[1];
    const float* v = (const float*)d_in[2];
    float* ctx  = (float*)d_out;
    float* attn = (float*)d_out + (size_t)BH_ * S_ * DK_;  // context first, then attn

    dim3 grid(BH_ * (S_ / TQ_));  // 32 * 256 = 8192 blocks
    dim3 block(NT_);
    sdpa_fused_kernel<<<grid, block, 0, stream>>>(q, k, v, ctx, attn);
}